// Round 2
// baseline (1042.544 us; speedup 1.0000x reference)
//
#include <hip/hip_runtime.h>

// ---------------------------------------------------------------------------
// RetnetBlock: LN1 -> proj(4D) -> split q,k,v,xo -> scores=QK^T*decay ->
// ret=S@V -> gate silu(xo) -> reto + residual -> LN2 -> FFN(gelu) + residual
// All GEMMs in fp16 MFMA (16x16x32), fp32 accumulate, fp32 residuals.
// R1: attention chunked per batch (S buffer 32MB not 128MB) + ws aliasing
//     (lnx/vT/hln share, gated<-Wp, ffh<-p). Total ws 114 MB (was 266 MB,
//     which overflowed d_ws -> GPU memory fault).
// ---------------------------------------------------------------------------

typedef _Float16 f16;
typedef _Float16 f16x8 __attribute__((ext_vector_type(8)));
typedef float floatx4 __attribute__((ext_vector_type(4)));

#define EP_BIAS_F16      0
#define EP_DECAY_F16     1
#define EP_GATE_F16      2
#define EP_BIAS_RES_F32  3
#define EP_BIAS_GELU_F16 4

// C[m,n] = sum_k A[m,k] * B[n,k]   (both operands K-contiguous, "BT" form)
// 256 threads = 4 waves in a 2x2 grid; wave tile = (WM*16) x (WN*16).
template <int BM, int BN, int WM, int WN, int EP>
__global__ __launch_bounds__(256) void gemm_bt(
    const f16* __restrict__ A, const f16* __restrict__ B, void* __restrict__ Cv,
    int M, int N, int K, int lda, int ldb, int ldc,
    long long sAo, long long sAi, long long sBo, long long sBi,
    long long sCo, long long sCi, int inner,
    const float* __restrict__ bias,
    const void* __restrict__ aux, long long sXo, long long sXi, int ldaux)
{
    const int zo = blockIdx.z / inner, zi = blockIdx.z % inner;
    A += zo * sAo + zi * sAi;
    B += zo * sBo + zi * sBi;
    const long long cOff = (long long)zo * sCo + (long long)zi * sCi;
    const long long xOff = (long long)zo * sXo + (long long)zi * sXi;

    const int m0 = blockIdx.y * BM;
    const int n0 = blockIdx.x * BN;

    __shared__ f16 As[BM * 32];
    __shared__ f16 Bs[BN * 32];

    const int t    = threadIdx.x;
    const int lane = t & 63;
    const int w    = t >> 6;
    const int wm   = (w >> 1) * (WM * 16);
    const int wn   = (w & 1) * (WN * 16);
    const int fr   = lane & 15;          // A row / B row within 16-tile
    const int fq   = (lane >> 4) * 8;    // k offset of this quad

    constexpr int ACH = (BM * 4) / 256;  // 16B chunks per thread for A tile
    constexpr int BCH = (BN * 4) / 256;

    floatx4 acc[WM][WN] = {};

    for (int kk = 0; kk < K; kk += 32) {
        uint4 ra[ACH], rb[BCH];
#pragma unroll
        for (int i = 0; i < ACH; ++i) {
            int ci = t + i * 256;
            int r = ci >> 2, c = (ci & 3) * 8;
            ra[i] = *(const uint4*)(A + (size_t)(m0 + r) * lda + kk + c);
        }
#pragma unroll
        for (int i = 0; i < BCH; ++i) {
            int ci = t + i * 256;
            int r = ci >> 2, c = (ci & 3) * 8;
            rb[i] = *(const uint4*)(B + (size_t)(n0 + r) * ldb + kk + c);
        }
        __syncthreads();
#pragma unroll
        for (int i = 0; i < ACH; ++i) { int ci = t + i * 256; *(uint4*)&As[ci * 8] = ra[i]; }
#pragma unroll
        for (int i = 0; i < BCH; ++i) { int ci = t + i * 256; *(uint4*)&Bs[ci * 8] = rb[i]; }
        __syncthreads();

        f16x8 af[WM], bf[WN];
#pragma unroll
        for (int tm = 0; tm < WM; ++tm)
            af[tm] = *(const f16x8*)&As[(wm + tm * 16 + fr) * 32 + fq];
#pragma unroll
        for (int tn = 0; tn < WN; ++tn)
            bf[tn] = *(const f16x8*)&Bs[(wn + tn * 16 + fr) * 32 + fq];
#pragma unroll
        for (int tm = 0; tm < WM; ++tm)
#pragma unroll
            for (int tn = 0; tn < WN; ++tn)
                acc[tm][tn] = __builtin_amdgcn_mfma_f32_16x16x32_f16(af[tm], bf[tn], acc[tm][tn], 0, 0, 0);
    }

    // epilogue: C/D layout col=lane&15, row=(lane>>4)*4+reg  [measured m89]
    const int er = (lane >> 4) * 4;
    const int ec = lane & 15;
#pragma unroll
    for (int tm = 0; tm < WM; ++tm) {
#pragma unroll
        for (int tn = 0; tn < WN; ++tn) {
#pragma unroll
            for (int r = 0; r < 4; ++r) {
                const int row = m0 + wm + tm * 16 + er + r;
                const int col = n0 + wn + tn * 16 + ec;
                const float v = acc[tm][tn][r];
                const size_t cidx = (size_t)(cOff + (long long)row * ldc + col);
                if constexpr (EP == EP_BIAS_F16) {
                    ((f16*)Cv)[cidx] = (f16)(v + bias[col]);
                } else if constexpr (EP == EP_DECAY_F16) {
                    const float* dk = (const float*)aux + xOff;
                    ((f16*)Cv)[cidx] = (f16)(v * dk[(size_t)row * ldaux + col]);
                } else if constexpr (EP == EP_GATE_F16) {
                    const f16* gt = (const f16*)aux + xOff;
                    float g = (float)gt[(size_t)row * ldaux + col];
                    g = g / (1.f + expf(-g));
                    ((f16*)Cv)[cidx] = (f16)(v * g);
                } else if constexpr (EP == EP_BIAS_RES_F32) {
                    const float* rs = (const float*)aux + xOff;
                    ((float*)Cv)[cidx] = v + bias[col] + rs[(size_t)row * ldaux + col];
                } else if constexpr (EP == EP_BIAS_GELU_F16) {
                    float u = v + bias[col];
                    u = 0.5f * u * (1.f + erff(u * 0.70710678118f));
                    ((f16*)Cv)[cidx] = (f16)u;
                }
            }
        }
    }
}

// LayerNorm over D=1024, one block (256 thr) per row, fp16 output.
__global__ __launch_bounds__(256) void ln_to_f16(
    const float* __restrict__ x, const float* __restrict__ g,
    const float* __restrict__ b, f16* __restrict__ out)
{
    const int row = blockIdx.x;
    const int t = threadIdx.x;
    const float4 xv = ((const float4*)(x + (size_t)row * 1024))[t];
    float s  = xv.x + xv.y + xv.z + xv.w;
    float ss = xv.x * xv.x + xv.y * xv.y + xv.z * xv.z + xv.w * xv.w;
    for (int o = 32; o > 0; o >>= 1) {
        s  += __shfl_down(s, o, 64);
        ss += __shfl_down(ss, o, 64);
    }
    __shared__ float red[8];
    const int wv = t >> 6;
    if ((t & 63) == 0) { red[wv] = s; red[wv + 4] = ss; }
    __syncthreads();
    s  = red[0] + red[1] + red[2] + red[3];
    ss = red[4] + red[5] + red[6] + red[7];
    const float mean = s * (1.f / 1024.f);
    const float var  = ss * (1.f / 1024.f) - mean * mean;
    const float rstd = rsqrtf(var + 1e-5f);
    const float4 gv = ((const float4*)g)[t];
    const float4 bv = ((const float4*)b)[t];
    alignas(8) f16 h[4];
    h[0] = (f16)((xv.x - mean) * rstd * gv.x + bv.x);
    h[1] = (f16)((xv.y - mean) * rstd * gv.y + bv.y);
    h[2] = (f16)((xv.z - mean) * rstd * gv.z + bv.z);
    h[3] = (f16)((xv.w - mean) * rstd * gv.w + bv.w);
    ((uint2*)(out + (size_t)row * 1024))[t] = *(uint2*)h;
}

// f32 -> f16 cast, 4 elems/thread
__global__ __launch_bounds__(256) void cast_f32_f16(
    const float* __restrict__ in, f16* __restrict__ out, int n4)
{
    const int i = blockIdx.x * 256 + threadIdx.x;
    if (i < n4) {
        const float4 v = ((const float4*)in)[i];
        alignas(8) f16 h[4] = {(f16)v.x, (f16)v.y, (f16)v.z, (f16)v.w};
        ((uint2*)out)[i] = *(uint2*)h;
    }
}

// vT[z=(b*16+h)][d][m] = p[b*1024+m][2048 + h*64 + d]   (64x64 LDS tile)
__global__ __launch_bounds__(256) void transpose_v(
    const f16* __restrict__ p, f16* __restrict__ vT)
{
    const int z = blockIdx.y;
    const int b = z >> 4, h = z & 15;
    const int m0 = blockIdx.x * 64;
    __shared__ f16 tile[64][72];
    const int t = threadIdx.x;
    const f16* src = p + (size_t)(b * 1024 + m0) * 4096 + 2048 + h * 64;
#pragma unroll
    for (int pass = 0; pass < 4; ++pass) {
        const int r = (t >> 4) + pass * 16;   // m
        const int c = (t & 15) * 4;           // d
        *(uint2*)&tile[r][c] = *(const uint2*)(src + (size_t)r * 4096 + c);
    }
    __syncthreads();
    f16* dst = vT + (size_t)z * 65536 + m0;
#pragma unroll
    for (int pass = 0; pass < 4; ++pass) {
        const int d  = (t >> 4) + pass * 16;
        const int mc = (t & 15) * 4;
        alignas(8) f16 tmp[4] = {tile[mc][d], tile[mc + 1][d], tile[mc + 2][d], tile[mc + 3][d]};
        *(uint2*)(dst + (size_t)d * 1024 + mc) = *(uint2*)tmp;
    }
}

extern "C" void kernel_launch(void* const* d_in, const int* in_sizes, int n_in,
                              void* d_out, int out_size, void* d_ws, size_t ws_size,
                              hipStream_t stream) {
    const float* x      = (const float*)d_in[0];
    const float* decay  = (const float*)d_in[1];
    const float* ln1_g  = (const float*)d_in[2];
    const float* ln1_b  = (const float*)d_in[3];
    const float* proj_W = (const float*)d_in[4];
    const float* proj_b = (const float*)d_in[5];
    const float* reto_W = (const float*)d_in[6];
    const float* reto_b = (const float*)d_in[7];
    const float* ln2_g  = (const float*)d_in[8];
    const float* ln2_b  = (const float*)d_in[9];
    const float* ffn1_W = (const float*)d_in[10];
    const float* ffn1_b = (const float*)d_in[11];
    const float* ffn2_W = (const float*)d_in[12];
    const float* ffn2_b = (const float*)d_in[13];
    float* out = (float*)d_out;

    // Workspace plan (114 MB total, liveness-aliased):
    //   Wp   8MB  [cast..G1]        -> reused as gated [G3..G4]
    //   Wr   2MB  [cast..G4]
    //   W1   8MB  [cast..G5]
    //   W2   8MB  [cast..G6]
    //   buf8 8MB  lnx[LN1..G1] -> vT[transpose..G3] -> hln[LN2..G5]
    //   p    32MB [G1..G3]          -> reused as ffh [G5..G6]
    //   S    32MB per-batch scores  [G2b..G3b]
    //   y    16MB [G4..G6]
    char* w = (char*)d_ws;
    auto alloc = [&](size_t bytes) { char* r = w; w += (bytes + 255) & ~(size_t)255; return r; };
    f16*   Wp   = (f16*)alloc((size_t)4096 * 1024 * 2);
    f16*   Wr   = (f16*)alloc((size_t)1024 * 1024 * 2);
    f16*   W1   = (f16*)alloc((size_t)4096 * 1024 * 2);
    f16*   W2   = (f16*)alloc((size_t)1024 * 4096 * 2);
    f16*   buf8 = (f16*)alloc((size_t)4096 * 1024 * 2);
    f16*   p    = (f16*)alloc((size_t)4096 * 4096 * 2);
    f16*   S    = (f16*)alloc((size_t)16 * 1024 * 1024 * 2);
    float* y    = (float*)alloc((size_t)4096 * 1024 * 4);

    f16* lnx   = buf8;
    f16* vT    = buf8;
    f16* hln   = buf8;
    f16* gated = Wp;
    f16* ffh   = p;

    // weight casts
    cast_f32_f16<<<4096, 256, 0, stream>>>(proj_W, Wp, 1048576);
    cast_f32_f16<<<1024, 256, 0, stream>>>(reto_W, Wr, 262144);
    cast_f32_f16<<<4096, 256, 0, stream>>>(ffn1_W, W1, 1048576);
    cast_f32_f16<<<4096, 256, 0, stream>>>(ffn2_W, W2, 1048576);

    // LN1
    ln_to_f16<<<4096, 256, 0, stream>>>(x, ln1_g, ln1_b, lnx);

    // G1: p = lnx @ proj_W^T + proj_b     [4096,4096]
    gemm_bt<128, 128, 4, 4, EP_BIAS_F16><<<dim3(32, 32, 1), 256, 0, stream>>>(
        lnx, Wp, p, 4096, 4096, 1024, 1024, 1024, 4096,
        0, 0, 0, 0, 0, 0, 1, proj_b, nullptr, 0, 0, 0);

    // v transpose (overwrites lnx region, dead after G1)
    transpose_v<<<dim3(16, 64), 256, 0, stream>>>(p, vT);

    // Attention, chunked per batch b (S reused; stream order serializes)
    for (int b = 0; b < 4; ++b) {
        const f16* qb = p + (size_t)b * 4194304;
        const f16* kb = p + 1024 + (size_t)b * 4194304;
        // G2b: S[h] = q_b @ k_b^T * decay[h]     [1024,1024] K=64, z=h
        gemm_bt<128, 128, 4, 4, EP_DECAY_F16><<<dim3(8, 8, 16), 256, 0, stream>>>(
            qb, kb, S, 1024, 1024, 64, 4096, 4096, 1024,
            0, 64, 0, 64, 0, 1048576, 16,
            nullptr, decay, 0, 1048576, 1024);
        // G3b: gated_b[l, h*64+d] = (S[h] @ vT_bh^T) * silu(xo_b)  [1024,64] K=1024
        gemm_bt<128, 64, 4, 2, EP_GATE_F16><<<dim3(1, 8, 16), 256, 0, stream>>>(
            S, vT + (size_t)b * 1048576, gated + (size_t)b * 1048576,
            1024, 64, 1024, 1024, 1024, 1024,
            0, 1048576, 0, 65536, 0, 64, 16,
            nullptr, p + 3072 + (size_t)b * 4194304, 0, 64, 4096);
    }

    // G4: y = gated @ reto_W^T + reto_b + x   (f32)
    gemm_bt<128, 128, 4, 4, EP_BIAS_RES_F32><<<dim3(8, 32, 1), 256, 0, stream>>>(
        gated, Wr, y, 4096, 1024, 1024, 1024, 1024, 1024,
        0, 0, 0, 0, 0, 0, 1, reto_b, x, 0, 0, 1024);

    // LN2 (hln overwrites vT region, dead after attention)
    ln_to_f16<<<4096, 256, 0, stream>>>(y, ln2_g, ln2_b, hln);

    // G5: ffh = gelu(hln @ ffn1_W^T + ffn1_b)   [4096,4096]  (ffh aliases p)
    gemm_bt<128, 128, 4, 4, EP_BIAS_GELU_F16><<<dim3(32, 32, 1), 256, 0, stream>>>(
        hln, W1, ffh, 4096, 4096, 1024, 1024, 1024, 4096,
        0, 0, 0, 0, 0, 0, 1, ffn1_b, nullptr, 0, 0, 0);

    // G6: out = ffh @ ffn2_W^T + ffn2_b + y   (f32)
    gemm_bt<128, 128, 4, 4, EP_BIAS_RES_F32><<<dim3(8, 32, 1), 256, 0, stream>>>(
        ffh, W2, out, 4096, 1024, 4096, 4096, 4096, 1024,
        0, 0, 0, 0, 0, 0, 1, ffn2_b, y, 0, 0, 1024);
}

// Round 3
// 956.252 us; speedup vs baseline: 1.0902x; 1.0902x over previous
//
#include <hip/hip_runtime.h>

// ---------------------------------------------------------------------------
// RetnetBlock fp16-MFMA implementation.
// R2: split-K + BN=64 for the skinny-N GEMMs (G3/G4/G6) which were
//     latency-bound at 1-2 waves/SIMD (Occ 11%, Mfma 6%). Partials (f32)
//     alias dead ws regions; bias/residual/silu-gate epilogues move into
//     vectorized reduce kernels. ws stays at 114 MB.
// ---------------------------------------------------------------------------

typedef _Float16 f16;
typedef _Float16 f16x8 __attribute__((ext_vector_type(8)));
typedef float floatx4 __attribute__((ext_vector_type(4)));

#define EP_BIAS_F16      0
#define EP_DECAY_F16     1
#define EP_BIAS_RES_F32  3
#define EP_BIAS_GELU_F16 4
#define EP_PARTIAL_F32   5

// C[m,n] = sum_k A[m,k] * B[n,k]  ("BT" form). 256 thr = 4 waves, 2x2 grid.
// blockIdx.z packs (zo*inner + zi)*nsplit + ks; split ks covers K-range
// [ks*Kc, (ks+1)*Kc), partial written at cOff + ks*sCk (EP_PARTIAL_F32).
template <int BM, int BN, int WM, int WN, int EP>
__global__ __launch_bounds__(256) void gemm_bt(
    const f16* __restrict__ A, const f16* __restrict__ B, void* __restrict__ Cv,
    int M, int N, int K, int lda, int ldb, int ldc,
    long long sAo, long long sAi, long long sBo, long long sBi,
    long long sCo, long long sCi, int inner,
    int nsplit, int Kc, long long sCk,
    const float* __restrict__ bias,
    const void* __restrict__ aux, long long sXo, long long sXi, int ldaux)
{
    int z = blockIdx.z;
    const int ks = z % nsplit; z /= nsplit;
    const int zo = z / inner, zi = z % inner;
    A += zo * sAo + zi * sAi;
    B += zo * sBo + zi * sBi;
    const long long cOff = (long long)zo * sCo + (long long)zi * sCi + (long long)ks * sCk;
    const long long xOff = (long long)zo * sXo + (long long)zi * sXi;

    const int m0 = blockIdx.y * BM;
    const int n0 = blockIdx.x * BN;

    __shared__ f16 As[BM * 32];
    __shared__ f16 Bs[BN * 32];

    const int t    = threadIdx.x;
    const int lane = t & 63;
    const int w    = t >> 6;
    const int wm   = (w >> 1) * (WM * 16);
    const int wn   = (w & 1) * (WN * 16);
    const int fr   = lane & 15;          // A row / B row within 16-tile
    const int fq   = (lane >> 4) * 8;    // k offset of this quad

    constexpr int ACH = (BM * 4) / 256;  // 16B chunks per thread for A tile
    constexpr int BCH = (BN * 4) / 256;

    floatx4 acc[WM][WN] = {};

    const int kbeg = ks * Kc, kend = kbeg + Kc;
    for (int kk = kbeg; kk < kend; kk += 32) {
        uint4 ra[ACH], rb[BCH];
#pragma unroll
        for (int i = 0; i < ACH; ++i) {
            int ci = t + i * 256;
            int r = ci >> 2, c = (ci & 3) * 8;
            ra[i] = *(const uint4*)(A + (size_t)(m0 + r) * lda + kk + c);
        }
#pragma unroll
        for (int i = 0; i < BCH; ++i) {
            int ci = t + i * 256;
            int r = ci >> 2, c = (ci & 3) * 8;
            rb[i] = *(const uint4*)(B + (size_t)(n0 + r) * ldb + kk + c);
        }
        __syncthreads();
#pragma unroll
        for (int i = 0; i < ACH; ++i) { int ci = t + i * 256; *(uint4*)&As[ci * 8] = ra[i]; }
#pragma unroll
        for (int i = 0; i < BCH; ++i) { int ci = t + i * 256; *(uint4*)&Bs[ci * 8] = rb[i]; }
        __syncthreads();

        f16x8 af[WM], bf[WN];
#pragma unroll
        for (int tm = 0; tm < WM; ++tm)
            af[tm] = *(const f16x8*)&As[(wm + tm * 16 + fr) * 32 + fq];
#pragma unroll
        for (int tn = 0; tn < WN; ++tn)
            bf[tn] = *(const f16x8*)&Bs[(wn + tn * 16 + fr) * 32 + fq];
#pragma unroll
        for (int tm = 0; tm < WM; ++tm)
#pragma unroll
            for (int tn = 0; tn < WN; ++tn)
                acc[tm][tn] = __builtin_amdgcn_mfma_f32_16x16x32_f16(af[tm], bf[tn], acc[tm][tn], 0, 0, 0);
    }

    // epilogue: C/D layout col=lane&15, row=(lane>>4)*4+reg  [measured m89]
    const int er = (lane >> 4) * 4;
    const int ec = lane & 15;
#pragma unroll
    for (int tm = 0; tm < WM; ++tm) {
#pragma unroll
        for (int tn = 0; tn < WN; ++tn) {
#pragma unroll
            for (int r = 0; r < 4; ++r) {
                const int row = m0 + wm + tm * 16 + er + r;
                const int col = n0 + wn + tn * 16 + ec;
                const float v = acc[tm][tn][r];
                const size_t cidx = (size_t)(cOff + (long long)row * ldc + col);
                if constexpr (EP == EP_BIAS_F16) {
                    ((f16*)Cv)[cidx] = (f16)(v + bias[col]);
                } else if constexpr (EP == EP_DECAY_F16) {
                    const float* dk = (const float*)aux + xOff;
                    ((f16*)Cv)[cidx] = (f16)(v * dk[(size_t)row * ldaux + col]);
                } else if constexpr (EP == EP_BIAS_RES_F32) {
                    const float* rs = (const float*)aux + xOff;
                    ((float*)Cv)[cidx] = v + bias[col] + rs[(size_t)row * ldaux + col];
                } else if constexpr (EP == EP_BIAS_GELU_F16) {
                    float u = v + bias[col];
                    u = 0.5f * u * (1.f + erff(u * 0.70710678118f));
                    ((f16*)Cv)[cidx] = (f16)u;
                } else if constexpr (EP == EP_PARTIAL_F32) {
                    ((float*)Cv)[cidx] = v;
                }
            }
        }
    }
}

// out[4096,1024] = P0 + P1 + bias[col] + res   (all f32, float4 vectorized)
__global__ __launch_bounds__(256) void reduce2_bias_res(
    const float4* __restrict__ P, const float* __restrict__ bias,
    const float4* __restrict__ res, float4* __restrict__ out)
{
    const int i = blockIdx.x * 256 + threadIdx.x;   // 1,048,576 groups
    const int col4 = i & 255;
    const float4 a = P[i];
    const float4 b = P[i + 1048576];
    const float4 r = res[i];
    const float4 bi = ((const float4*)bias)[col4];
    float4 o;
    o.x = a.x + b.x + r.x + bi.x;
    o.y = a.y + b.y + r.y + bi.y;
    o.z = a.z + b.z + r.z + bi.z;
    o.w = a.w + b.w + r.w + bi.w;
    out[i] = o;
}

// gated_b[l, h*64+d] = (sum_ks P[h][ks][l][d]) * silu(xo_b[l, h*64+d])
__global__ __launch_bounds__(256) void reduce_gate(
    const float* __restrict__ P, const f16* __restrict__ xo, f16* __restrict__ gated)
{
    const int i = blockIdx.x * 256 + threadIdx.x;   // 262,144 groups of 4
    const int c = (i * 4) & 1023;
    const int l = (i * 4) >> 10;
    const int h = c >> 6, d = c & 63;
    const size_t base = (size_t)h * 262144 + (size_t)l * 64 + d;
    float4 s = {0.f, 0.f, 0.f, 0.f};
#pragma unroll
    for (int ks = 0; ks < 4; ++ks) {
        const float4 v = *(const float4*)(P + base + (size_t)ks * 65536);
        s.x += v.x; s.y += v.y; s.z += v.z; s.w += v.w;
    }
    alignas(8) f16 g[4];
    *(uint2*)g = *(const uint2*)(xo + (size_t)l * 4096 + c);
    alignas(8) f16 o[4];
    float sv[4] = {s.x, s.y, s.z, s.w};
#pragma unroll
    for (int j = 0; j < 4; ++j) {
        float gv = (float)g[j];
        gv = gv / (1.f + expf(-gv));
        o[j] = (f16)(sv[j] * gv);
    }
    *(uint2*)(gated + (size_t)l * 1024 + c) = *(uint2*)o;
}

// LayerNorm over D=1024, one block (256 thr) per row, fp16 output.
__global__ __launch_bounds__(256) void ln_to_f16(
    const float* __restrict__ x, const float* __restrict__ g,
    const float* __restrict__ b, f16* __restrict__ out)
{
    const int row = blockIdx.x;
    const int t = threadIdx.x;
    const float4 xv = ((const float4*)(x + (size_t)row * 1024))[t];
    float s  = xv.x + xv.y + xv.z + xv.w;
    float ss = xv.x * xv.x + xv.y * xv.y + xv.z * xv.z + xv.w * xv.w;
    for (int o = 32; o > 0; o >>= 1) {
        s  += __shfl_down(s, o, 64);
        ss += __shfl_down(ss, o, 64);
    }
    __shared__ float red[8];
    const int wv = t >> 6;
    if ((t & 63) == 0) { red[wv] = s; red[wv + 4] = ss; }
    __syncthreads();
    s  = red[0] + red[1] + red[2] + red[3];
    ss = red[4] + red[5] + red[6] + red[7];
    const float mean = s * (1.f / 1024.f);
    const float var  = ss * (1.f / 1024.f) - mean * mean;
    const float rstd = rsqrtf(var + 1e-5f);
    const float4 gv = ((const float4*)g)[t];
    const float4 bv = ((const float4*)b)[t];
    alignas(8) f16 h[4];
    h[0] = (f16)((xv.x - mean) * rstd * gv.x + bv.x);
    h[1] = (f16)((xv.y - mean) * rstd * gv.y + bv.y);
    h[2] = (f16)((xv.z - mean) * rstd * gv.z + bv.z);
    h[3] = (f16)((xv.w - mean) * rstd * gv.w + bv.w);
    ((uint2*)(out + (size_t)row * 1024))[t] = *(uint2*)h;
}

// f32 -> f16 cast, 4 elems/thread
__global__ __launch_bounds__(256) void cast_f32_f16(
    const float* __restrict__ in, f16* __restrict__ out, int n4)
{
    const int i = blockIdx.x * 256 + threadIdx.x;
    if (i < n4) {
        const float4 v = ((const float4*)in)[i];
        alignas(8) f16 h[4] = {(f16)v.x, (f16)v.y, (f16)v.z, (f16)v.w};
        ((uint2*)out)[i] = *(uint2*)h;
    }
}

// vT[z=(b*16+h)][d][m] = p[b*1024+m][2048 + h*64 + d]   (64x64 LDS tile)
__global__ __launch_bounds__(256) void transpose_v(
    const f16* __restrict__ p, f16* __restrict__ vT)
{
    const int z = blockIdx.y;
    const int b = z >> 4, h = z & 15;
    const int m0 = blockIdx.x * 64;
    __shared__ f16 tile[64][72];
    const int t = threadIdx.x;
    const f16* src = p + (size_t)(b * 1024 + m0) * 4096 + 2048 + h * 64;
#pragma unroll
    for (int pass = 0; pass < 4; ++pass) {
        const int r = (t >> 4) + pass * 16;   // m
        const int c = (t & 15) * 4;           // d
        *(uint2*)&tile[r][c] = *(const uint2*)(src + (size_t)r * 4096 + c);
    }
    __syncthreads();
    f16* dst = vT + (size_t)z * 65536 + m0;
#pragma unroll
    for (int pass = 0; pass < 4; ++pass) {
        const int d  = (t >> 4) + pass * 16;
        const int mc = (t & 15) * 4;
        alignas(8) f16 tmp[4] = {tile[mc][d], tile[mc + 1][d], tile[mc + 2][d], tile[mc + 3][d]};
        *(uint2*)(dst + (size_t)d * 1024 + mc) = *(uint2*)tmp;
    }
}

extern "C" void kernel_launch(void* const* d_in, const int* in_sizes, int n_in,
                              void* d_out, int out_size, void* d_ws, size_t ws_size,
                              hipStream_t stream) {
    const float* x      = (const float*)d_in[0];
    const float* decay  = (const float*)d_in[1];
    const float* ln1_g  = (const float*)d_in[2];
    const float* ln1_b  = (const float*)d_in[3];
    const float* proj_W = (const float*)d_in[4];
    const float* proj_b = (const float*)d_in[5];
    const float* reto_W = (const float*)d_in[6];
    const float* reto_b = (const float*)d_in[7];
    const float* ln2_g  = (const float*)d_in[8];
    const float* ln2_b  = (const float*)d_in[9];
    const float* ffn1_W = (const float*)d_in[10];
    const float* ffn1_b = (const float*)d_in[11];
    const float* ffn2_W = (const float*)d_in[12];
    const float* ffn2_b = (const float*)d_in[13];
    float* out = (float*)d_out;

    // Workspace (114 MB, liveness-aliased):
    //   Wp 8MB [cast..G1] -> gated [G3red..G4]
    //   Wr 2MB, W1 8MB, W2 8MB
    //   buf8 8MB: lnx[LN1..G1] -> vT[transp..G3] -> hln[LN2..G5]
    //   p 32MB [G1..G3red(xo)] -> ffh [G5..G6]
    //   S 32MB: scores per batch [G2..G3]; then G4/G6 splitK partials (2x16MB)
    //   y 16MB: G3 splitK partials per batch [G3..G3red]; then y [G4red..G6]
    char* w = (char*)d_ws;
    auto alloc = [&](size_t bytes) { char* r = w; w += (bytes + 255) & ~(size_t)255; return r; };
    f16*   Wp   = (f16*)alloc((size_t)4096 * 1024 * 2);
    f16*   Wr   = (f16*)alloc((size_t)1024 * 1024 * 2);
    f16*   W1   = (f16*)alloc((size_t)4096 * 1024 * 2);
    f16*   W2   = (f16*)alloc((size_t)1024 * 4096 * 2);
    f16*   buf8 = (f16*)alloc((size_t)4096 * 1024 * 2);
    f16*   p    = (f16*)alloc((size_t)4096 * 4096 * 2);
    f16*   S    = (f16*)alloc((size_t)16 * 1024 * 1024 * 2);
    float* y    = (float*)alloc((size_t)4096 * 1024 * 4);

    f16*   lnx   = buf8;
    f16*   vT    = buf8;
    f16*   hln   = buf8;
    f16*   gated = Wp;
    f16*   ffh   = p;
    float* Pk    = (float*)S;   // split-K partials for G4/G6 (2 x 16MB)
    float* Pg    = y;           // split-K partials for G3 (16MB, per batch)

    // weight casts
    cast_f32_f16<<<4096, 256, 0, stream>>>(proj_W, Wp, 1048576);
    cast_f32_f16<<<1024, 256, 0, stream>>>(reto_W, Wr, 262144);
    cast_f32_f16<<<4096, 256, 0, stream>>>(ffn1_W, W1, 1048576);
    cast_f32_f16<<<4096, 256, 0, stream>>>(ffn2_W, W2, 1048576);

    // LN1
    ln_to_f16<<<4096, 256, 0, stream>>>(x, ln1_g, ln1_b, lnx);

    // G1: p = lnx @ proj_W^T + proj_b     [4096,4096] K=1024
    gemm_bt<128, 128, 4, 4, EP_BIAS_F16><<<dim3(32, 32, 1), 256, 0, stream>>>(
        lnx, Wp, p, 4096, 4096, 1024, 1024, 1024, 4096,
        0, 0, 0, 0, 0, 0, 1, 1, 1024, 0, proj_b, nullptr, 0, 0, 0);

    // v transpose (overwrites lnx, dead after G1)
    transpose_v<<<dim3(16, 64), 256, 0, stream>>>(p, vT);

    // Attention, chunked per batch (S + Pg reused; stream order serializes)
    for (int b = 0; b < 4; ++b) {
        const f16* qb = p + (size_t)b * 4194304;
        const f16* kb = p + 1024 + (size_t)b * 4194304;
        // G2b: S[h] = q_b @ k_b^T * decay[h]   [1024,1024] K=64, z=h
        gemm_bt<128, 128, 4, 4, EP_DECAY_F16><<<dim3(8, 8, 16), 256, 0, stream>>>(
            qb, kb, S, 1024, 1024, 64, 4096, 4096, 1024,
            0, 64, 0, 64, 0, 1048576, 16, 1, 64, 0,
            nullptr, decay, 0, 1048576, 1024);
        // G3b: Pg[h][ks][l][d] = S[h] @ vT_bh^T over K-chunk ks  (split-K=4)
        gemm_bt<128, 64, 4, 2, EP_PARTIAL_F32><<<dim3(1, 8, 64), 256, 0, stream>>>(
            S, vT + (size_t)b * 1048576, Pg, 1024, 64, 1024, 1024, 1024, 64,
            0, 1048576, 0, 65536, 0, 262144, 16, 4, 256, 65536,
            nullptr, nullptr, 0, 0, 0);
        // gate: gated_b = (sum Pg) * silu(xo_b)
        reduce_gate<<<1024, 256, 0, stream>>>(
            Pg, p + 3072 + (size_t)b * 4194304, gated + (size_t)b * 1048576);
    }

    // G4: Pk = gated @ reto_W^T  (split-K=2, Kc=512) -> y = +reto_b + x
    gemm_bt<128, 64, 4, 2, EP_PARTIAL_F32><<<dim3(16, 32, 2), 256, 0, stream>>>(
        gated, Wr, Pk, 4096, 1024, 1024, 1024, 1024, 1024,
        0, 0, 0, 0, 0, 0, 1, 2, 512, 4194304, nullptr, nullptr, 0, 0, 0);
    reduce2_bias_res<<<4096, 256, 0, stream>>>(
        (const float4*)Pk, reto_b, (const float4*)x, (float4*)y);

    // LN2
    ln_to_f16<<<4096, 256, 0, stream>>>(y, ln2_g, ln2_b, hln);

    // G5: ffh = gelu(hln @ ffn1_W^T + ffn1_b)   [4096,4096] K=1024
    gemm_bt<128, 128, 4, 4, EP_BIAS_GELU_F16><<<dim3(32, 32, 1), 256, 0, stream>>>(
        hln, W1, ffh, 4096, 4096, 1024, 1024, 1024, 4096,
        0, 0, 0, 0, 0, 0, 1, 1, 1024, 0, ffn1_b, nullptr, 0, 0, 0);

    // G6: Pk = ffh @ ffn2_W^T (split-K=2, Kc=2048) -> out = +ffn2_b + y
    gemm_bt<128, 64, 4, 2, EP_PARTIAL_F32><<<dim3(16, 32, 2), 256, 0, stream>>>(
        ffh, W2, Pk, 4096, 1024, 4096, 4096, 4096, 1024,
        0, 0, 0, 0, 0, 0, 1, 2, 2048, 4194304, nullptr, nullptr, 0, 0, 0);
    reduce2_bias_res<<<4096, 256, 0, stream>>>(
        (const float4*)Pk, ffn2_b, (const float4*)y, (float4*)out);
}

// Round 4
// 627.184 us; speedup vs baseline: 1.6623x; 1.5247x over previous
//
#include <hip/hip_runtime.h>

// ---------------------------------------------------------------------------
// RetnetBlock fp16-MFMA implementation.
// R3: m97-class GEMM core: (a) global_load_lds width=16 async staging of A/B
//     tiles (wave-uniform LDS base + lane*16 layout), (b) epilogue C-writes
//     staged through LDS (64-row halves, +4-elem pad for bank spread) and
//     flushed with coalesced global_store_dwordx4. Fixes R3's 6x HBM write
//     amplification (189MB for a 32MB tile) and scalar-store epilogue.
// ---------------------------------------------------------------------------

typedef _Float16 f16;
typedef _Float16 f16x8 __attribute__((ext_vector_type(8)));
typedef float floatx4 __attribute__((ext_vector_type(4)));

#define EP_BIAS_F16      0
#define EP_DECAY_F16     1
#define EP_BIAS_GELU_F16 2
#define EP_PARTIAL_F32   3

template <bool F32> struct out_sel { typedef f16 T; };
template <> struct out_sel<true>   { typedef float T; };

__device__ __forceinline__ void gload_lds16(const void* g, void* s) {
    __builtin_amdgcn_global_load_lds(
        (const __attribute__((address_space(1))) unsigned int*)g,
        (__attribute__((address_space(3))) unsigned int*)s, 16, 0, 0);
}

// C[m,n] = sum_k A[m,k] * B[n,k]  ("BT" form). 256 thr = 4 waves, 2x2 grid.
// blockIdx.z packs ((zo*inner + zi)*nsplit + ks); split ks covers K-range
// [ks*Kc,(ks+1)*Kc), partial written at cOff + ks*sCk (EP_PARTIAL_F32).
template <int BM, int BN, int WM, int WN, int EP>
__global__ __launch_bounds__(256) void gemm_bt(
    const f16* __restrict__ A, const f16* __restrict__ B, void* __restrict__ Cv,
    int M, int N, int K, int lda, int ldb, int ldc,
    long long sAo, long long sAi, long long sBo, long long sBi,
    long long sCo, long long sCi, int inner,
    int nsplit, int Kc, long long sCk,
    const float* __restrict__ bias,
    const void* __restrict__ aux, long long sXo, long long sXi, int ldaux)
{
    constexpr bool OUT_F32 = (EP == EP_PARTIAL_F32);
    typedef typename out_sel<OUT_F32>::T OutT;
    constexpr int ESIZE        = OUT_F32 ? 4 : 2;
    constexpr int STRIDE       = BN + 4;                 // stage row stride, elems
    constexpr int TILE_BYTES   = (BM + BN) * 64;
    constexpr int STAGE_BYTES  = 64 * STRIDE * ESIZE;
    constexpr int SMEM_BYTES   = TILE_BYTES > STAGE_BYTES ? TILE_BYTES : STAGE_BYTES;

    __shared__ __align__(16) char smem[SMEM_BYTES];
    f16* As = (f16*)smem;
    f16* Bs = (f16*)(smem + BM * 64);
    OutT* Cs = (OutT*)smem;

    int z = blockIdx.z;
    const int ks = z % nsplit; z /= nsplit;
    const int zo = z / inner, zi = z % inner;
    A += zo * sAo + zi * sAi;
    B += zo * sBo + zi * sBi;
    const long long cOff = (long long)zo * sCo + (long long)zi * sCi + (long long)ks * sCk;
    const long long xOff = (long long)zo * sXo + (long long)zi * sXi;

    const int m0 = blockIdx.y * BM;
    const int n0 = blockIdx.x * BN;

    const int t    = threadIdx.x;
    const int lane = t & 63;
    const int w    = t >> 6;
    const int wm   = (w >> 1) * (WM * 16);
    const int wn   = (w & 1) * (WN * 16);
    const int fr   = lane & 15;          // A/B row within 16-tile
    const int fq   = (lane >> 4) * 8;    // k offset of this quad

    floatx4 acc[WM][WN] = {};

    const int kbeg = ks * Kc, kend = kbeg + Kc;
    for (int kk = kbeg; kk < kend; kk += 32) {
        // async global -> LDS staging, 16B/lane; LDS dest = chunk-index*16,
        // which is wave-uniform base + lane*16 by construction.
#pragma unroll
        for (int i = 0; i < BM / 64; ++i) {
            int ci = t + i * 256;
            int r = ci >> 2, c = (ci & 3) * 8;
            gload_lds16(A + (size_t)(m0 + r) * lda + kk + c, &As[ci * 8]);
        }
#pragma unroll
        for (int i = 0; i < BN / 64; ++i) {
            int ci = t + i * 256;
            int r = ci >> 2, c = (ci & 3) * 8;
            gload_lds16(B + (size_t)(n0 + r) * ldb + kk + c, &Bs[ci * 8]);
        }
        __syncthreads();

        f16x8 af[WM], bf[WN];
#pragma unroll
        for (int tm = 0; tm < WM; ++tm)
            af[tm] = *(const f16x8*)&As[(wm + tm * 16 + fr) * 32 + fq];
#pragma unroll
        for (int tn = 0; tn < WN; ++tn)
            bf[tn] = *(const f16x8*)&Bs[(wn + tn * 16 + fr) * 32 + fq];
#pragma unroll
        for (int tm = 0; tm < WM; ++tm)
#pragma unroll
            for (int tn = 0; tn < WN; ++tn)
                acc[tm][tn] = __builtin_amdgcn_mfma_f32_16x16x32_f16(af[tm], bf[tn], acc[tm][tn], 0, 0, 0);
        __syncthreads();
    }

    // ---- epilogue: C/D layout col=lane&15, row=(lane>>4)*4+reg [m89] ----
    // Stage 64-row halves through LDS, flush with coalesced dwordx4 stores.
    const int er = (lane >> 4) * 4;
    const int ec = lane & 15;
    constexpr int PER_ROW = BN * ESIZE / 16;          // 16B chunks per row
    constexpr int NCHUNK  = (64 * PER_ROW) / 256;     // chunks per thread

#pragma unroll
    for (int half = 0; half < 2; ++half) {
        if ((w >> 1) == half) {
#pragma unroll
            for (int tm = 0; tm < WM; ++tm) {
#pragma unroll
                for (int tn = 0; tn < WN; ++tn) {
#pragma unroll
                    for (int r = 0; r < 4; ++r) {
                        const int lrow = tm * 16 + er + r;        // 0..63
                        const int col  = wn + tn * 16 + ec;       // 0..BN-1
                        const int grow = m0 + half * 64 + lrow;
                        const int gcol = n0 + col;
                        const float v = acc[tm][tn][r];
                        float val;
                        if constexpr (EP == EP_BIAS_F16) {
                            val = v + bias[gcol];
                        } else if constexpr (EP == EP_DECAY_F16) {
                            const float* dk = (const float*)aux + xOff;
                            val = v * dk[(size_t)grow * ldaux + gcol];
                        } else if constexpr (EP == EP_BIAS_GELU_F16) {
                            float u = v + bias[gcol];
                            val = 0.5f * u * (1.f + erff(u * 0.70710678118f));
                        } else {
                            val = v;
                        }
                        Cs[lrow * STRIDE + col] = (OutT)val;
                    }
                }
            }
        }
        __syncthreads();
#pragma unroll
        for (int i = 0; i < NCHUNK; ++i) {
            const int j  = t + i * 256;
            const int rr = j / PER_ROW;
            const int cc = j - rr * PER_ROW;
            const char* src = smem + (size_t)rr * (STRIDE * ESIZE) + (size_t)cc * 16;
            uint4 val;
            if constexpr (OUT_F32) {
                val = *(const uint4*)src;                 // 16B-aligned (stride 272B)
            } else {
                const uint2 lo = *(const uint2*)src;      // stride 264B: 8B-aligned
                const uint2 hi = *(const uint2*)(src + 8);
                val = make_uint4(lo.x, lo.y, hi.x, hi.y);
            }
            char* dst = (char*)Cv +
                (size_t)(cOff + (long long)(m0 + half * 64 + rr) * ldc + n0) * ESIZE +
                (size_t)cc * 16;
            *(uint4*)dst = val;
        }
        __syncthreads();
    }
}

// out[4096,1024] = P0 + P1 + bias[col] + res   (all f32, float4 vectorized)
__global__ __launch_bounds__(256) void reduce2_bias_res(
    const float4* __restrict__ P, const float* __restrict__ bias,
    const float4* __restrict__ res, float4* __restrict__ out)
{
    const int i = blockIdx.x * 256 + threadIdx.x;   // 1,048,576 groups
    const int col4 = i & 255;
    const float4 a = P[i];
    const float4 b = P[i + 1048576];
    const float4 r = res[i];
    const float4 bi = ((const float4*)bias)[col4];
    float4 o;
    o.x = a.x + b.x + r.x + bi.x;
    o.y = a.y + b.y + r.y + bi.y;
    o.z = a.z + b.z + r.z + bi.z;
    o.w = a.w + b.w + r.w + bi.w;
    out[i] = o;
}

// gated_b[l, h*64+d] = (sum_ks P[h][ks][l][d]) * silu(xo_b[l, h*64+d])
__global__ __launch_bounds__(256) void reduce_gate(
    const float* __restrict__ P, const f16* __restrict__ xo, f16* __restrict__ gated)
{
    const int i = blockIdx.x * 256 + threadIdx.x;   // 262,144 groups of 4
    const int c = (i * 4) & 1023;
    const int l = (i * 4) >> 10;
    const int h = c >> 6, d = c & 63;
    const size_t base = (size_t)h * 262144 + (size_t)l * 64 + d;
    float4 s = {0.f, 0.f, 0.f, 0.f};
#pragma unroll
    for (int ks = 0; ks < 4; ++ks) {
        const float4 v = *(const float4*)(P + base + (size_t)ks * 65536);
        s.x += v.x; s.y += v.y; s.z += v.z; s.w += v.w;
    }
    alignas(8) f16 g[4];
    *(uint2*)g = *(const uint2*)(xo + (size_t)l * 4096 + c);
    alignas(8) f16 o[4];
    float sv[4] = {s.x, s.y, s.z, s.w};
#pragma unroll
    for (int j = 0; j < 4; ++j) {
        float gv = (float)g[j];
        gv = gv / (1.f + expf(-gv));
        o[j] = (f16)(sv[j] * gv);
    }
    *(uint2*)(gated + (size_t)l * 1024 + c) = *(uint2*)o;
}

// LayerNorm over D=1024, one block (256 thr) per row, fp16 output.
__global__ __launch_bounds__(256) void ln_to_f16(
    const float* __restrict__ x, const float* __restrict__ g,
    const float* __restrict__ b, f16* __restrict__ out)
{
    const int row = blockIdx.x;
    const int t = threadIdx.x;
    const float4 xv = ((const float4*)(x + (size_t)row * 1024))[t];
    float s  = xv.x + xv.y + xv.z + xv.w;
    float ss = xv.x * xv.x + xv.y * xv.y + xv.z * xv.z + xv.w * xv.w;
    for (int o = 32; o > 0; o >>= 1) {
        s  += __shfl_down(s, o, 64);
        ss += __shfl_down(ss, o, 64);
    }
    __shared__ float red[8];
    const int wv = t >> 6;
    if ((t & 63) == 0) { red[wv] = s; red[wv + 4] = ss; }
    __syncthreads();
    s  = red[0] + red[1] + red[2] + red[3];
    ss = red[4] + red[5] + red[6] + red[7];
    const float mean = s * (1.f / 1024.f);
    const float var  = ss * (1.f / 1024.f) - mean * mean;
    const float rstd = rsqrtf(var + 1e-5f);
    const float4 gv = ((const float4*)g)[t];
    const float4 bv = ((const float4*)b)[t];
    alignas(8) f16 h[4];
    h[0] = (f16)((xv.x - mean) * rstd * gv.x + bv.x);
    h[1] = (f16)((xv.y - mean) * rstd * gv.y + bv.y);
    h[2] = (f16)((xv.z - mean) * rstd * gv.z + bv.z);
    h[3] = (f16)((xv.w - mean) * rstd * gv.w + bv.w);
    ((uint2*)(out + (size_t)row * 1024))[t] = *(uint2*)h;
}

// f32 -> f16 cast, 4 elems/thread
__global__ __launch_bounds__(256) void cast_f32_f16(
    const float* __restrict__ in, f16* __restrict__ out, int n4)
{
    const int i = blockIdx.x * 256 + threadIdx.x;
    if (i < n4) {
        const float4 v = ((const float4*)in)[i];
        alignas(8) f16 h[4] = {(f16)v.x, (f16)v.y, (f16)v.z, (f16)v.w};
        ((uint2*)out)[i] = *(uint2*)h;
    }
}

// vT[z=(b*16+h)][d][m] = p[b*1024+m][2048 + h*64 + d]   (64x64 LDS tile)
__global__ __launch_bounds__(256) void transpose_v(
    const f16* __restrict__ p, f16* __restrict__ vT)
{
    const int z = blockIdx.y;
    const int b = z >> 4, h = z & 15;
    const int m0 = blockIdx.x * 64;
    __shared__ f16 tile[64][72];
    const int t = threadIdx.x;
    const f16* src = p + (size_t)(b * 1024 + m0) * 4096 + 2048 + h * 64;
#pragma unroll
    for (int pass = 0; pass < 4; ++pass) {
        const int r = (t >> 4) + pass * 16;   // m
        const int c = (t & 15) * 4;           // d
        *(uint2*)&tile[r][c] = *(const uint2*)(src + (size_t)r * 4096 + c);
    }
    __syncthreads();
    f16* dst = vT + (size_t)z * 65536 + m0;
#pragma unroll
    for (int pass = 0; pass < 4; ++pass) {
        const int d  = (t >> 4) + pass * 16;
        const int mc = (t & 15) * 4;
        alignas(8) f16 tmp[4] = {tile[mc][d], tile[mc + 1][d], tile[mc + 2][d], tile[mc + 3][d]};
        *(uint2*)(dst + (size_t)d * 1024 + mc) = *(uint2*)tmp;
    }
}

extern "C" void kernel_launch(void* const* d_in, const int* in_sizes, int n_in,
                              void* d_out, int out_size, void* d_ws, size_t ws_size,
                              hipStream_t stream) {
    const float* x      = (const float*)d_in[0];
    const float* decay  = (const float*)d_in[1];
    const float* ln1_g  = (const float*)d_in[2];
    const float* ln1_b  = (const float*)d_in[3];
    const float* proj_W = (const float*)d_in[4];
    const float* proj_b = (const float*)d_in[5];
    const float* reto_W = (const float*)d_in[6];
    const float* reto_b = (const float*)d_in[7];
    const float* ln2_g  = (const float*)d_in[8];
    const float* ln2_b  = (const float*)d_in[9];
    const float* ffn1_W = (const float*)d_in[10];
    const float* ffn1_b = (const float*)d_in[11];
    const float* ffn2_W = (const float*)d_in[12];
    const float* ffn2_b = (const float*)d_in[13];
    float* out = (float*)d_out;

    // Workspace (114 MB, liveness-aliased):
    //   Wp 8MB [cast..G1] -> gated [G3red..G4]
    //   Wr 2MB, W1 8MB, W2 8MB
    //   buf8 8MB: lnx[LN1..G1] -> vT[transp..G3] -> hln[LN2..G5]
    //   p 32MB [G1..G3red(xo)] -> ffh [G5..G6]
    //   S 32MB: scores per batch [G2..G3]; then G4/G6 splitK partials (2x16MB)
    //   y 16MB: G3 splitK partials per batch [G3..G3red]; then y [G4red..G6]
    char* w = (char*)d_ws;
    auto alloc = [&](size_t bytes) { char* r = w; w += (bytes + 255) & ~(size_t)255; return r; };
    f16*   Wp   = (f16*)alloc((size_t)4096 * 1024 * 2);
    f16*   Wr   = (f16*)alloc((size_t)1024 * 1024 * 2);
    f16*   W1   = (f16*)alloc((size_t)4096 * 1024 * 2);
    f16*   W2   = (f16*)alloc((size_t)1024 * 4096 * 2);
    f16*   buf8 = (f16*)alloc((size_t)4096 * 1024 * 2);
    f16*   p    = (f16*)alloc((size_t)4096 * 4096 * 2);
    f16*   S    = (f16*)alloc((size_t)16 * 1024 * 1024 * 2);
    float* y    = (float*)alloc((size_t)4096 * 1024 * 4);

    f16*   lnx   = buf8;
    f16*   vT    = buf8;
    f16*   hln   = buf8;
    f16*   gated = Wp;
    f16*   ffh   = p;
    float* Pk    = (float*)S;   // split-K partials for G4/G6 (2 x 16MB)
    float* Pg    = y;           // split-K partials for G3 (16MB, per batch)

    // weight casts
    cast_f32_f16<<<4096, 256, 0, stream>>>(proj_W, Wp, 1048576);
    cast_f32_f16<<<1024, 256, 0, stream>>>(reto_W, Wr, 262144);
    cast_f32_f16<<<4096, 256, 0, stream>>>(ffn1_W, W1, 1048576);
    cast_f32_f16<<<4096, 256, 0, stream>>>(ffn2_W, W2, 1048576);

    // LN1
    ln_to_f16<<<4096, 256, 0, stream>>>(x, ln1_g, ln1_b, lnx);

    // G1: p = lnx @ proj_W^T + proj_b     [4096,4096] K=1024
    gemm_bt<128, 128, 4, 4, EP_BIAS_F16><<<dim3(32, 32, 1), 256, 0, stream>>>(
        lnx, Wp, p, 4096, 4096, 1024, 1024, 1024, 4096,
        0, 0, 0, 0, 0, 0, 1, 1, 1024, 0, proj_b, nullptr, 0, 0, 0);

    // v transpose (overwrites lnx, dead after G1)
    transpose_v<<<dim3(16, 64), 256, 0, stream>>>(p, vT);

    // Attention, chunked per batch (S + Pg reused; stream order serializes)
    for (int b = 0; b < 4; ++b) {
        const f16* qb = p + (size_t)b * 4194304;
        const f16* kb = p + 1024 + (size_t)b * 4194304;
        // G2b: S[h] = q_b @ k_b^T * decay[h]   [1024,1024] K=64, z=h
        gemm_bt<128, 128, 4, 4, EP_DECAY_F16><<<dim3(8, 8, 16), 256, 0, stream>>>(
            qb, kb, S, 1024, 1024, 64, 4096, 4096, 1024,
            0, 64, 0, 64, 0, 1048576, 16, 1, 64, 0,
            nullptr, decay, 0, 1048576, 1024);
        // G3b: Pg[h][ks][l][d] = S[h] @ vT_bh^T over K-chunk ks  (split-K=4)
        gemm_bt<128, 64, 4, 2, EP_PARTIAL_F32><<<dim3(1, 8, 64), 256, 0, stream>>>(
            S, vT + (size_t)b * 1048576, Pg, 1024, 64, 1024, 1024, 1024, 64,
            0, 1048576, 0, 65536, 0, 262144, 16, 4, 256, 65536,
            nullptr, nullptr, 0, 0, 0);
        // gate: gated_b = (sum Pg) * silu(xo_b)
        reduce_gate<<<1024, 256, 0, stream>>>(
            Pg, p + 3072 + (size_t)b * 4194304, gated + (size_t)b * 1048576);
    }

    // G4: Pk = gated @ reto_W^T  (split-K=2, Kc=512) -> y = +reto_b + x
    gemm_bt<128, 64, 4, 2, EP_PARTIAL_F32><<<dim3(16, 32, 2), 256, 0, stream>>>(
        gated, Wr, Pk, 4096, 1024, 1024, 1024, 1024, 1024,
        0, 0, 0, 0, 0, 0, 1, 2, 512, 4194304, nullptr, nullptr, 0, 0, 0);
    reduce2_bias_res<<<4096, 256, 0, stream>>>(
        (const float4*)Pk, reto_b, (const float4*)x, (float4*)y);

    // LN2
    ln_to_f16<<<4096, 256, 0, stream>>>(y, ln2_g, ln2_b, hln);

    // G5: ffh = gelu(hln @ ffn1_W^T + ffn1_b)   [4096,4096] K=1024
    gemm_bt<128, 128, 4, 4, EP_BIAS_GELU_F16><<<dim3(32, 32, 1), 256, 0, stream>>>(
        hln, W1, ffh, 4096, 4096, 1024, 1024, 1024, 4096,
        0, 0, 0, 0, 0, 0, 1, 1, 1024, 0, ffn1_b, nullptr, 0, 0, 0);

    // G6: Pk = ffh @ ffn2_W^T (split-K=2, Kc=2048) -> out = +ffn2_b + y
    gemm_bt<128, 64, 4, 2, EP_PARTIAL_F32><<<dim3(16, 32, 2), 256, 0, stream>>>(
        ffh, W2, Pk, 4096, 1024, 4096, 4096, 4096, 1024,
        0, 0, 0, 0, 0, 0, 1, 2, 2048, 4194304, nullptr, nullptr, 0, 0, 0);
    reduce2_bias_res<<<4096, 256, 0, stream>>>(
        (const float4*)Pk, ffn2_b, (const float4*)y, (float4*)out);
}

// Round 5
// 501.904 us; speedup vs baseline: 2.0772x; 1.2496x over previous
//
#include <hip/hip_runtime.h>

// ---------------------------------------------------------------------------
// RetnetBlock fp16-MFMA implementation.
// R4: GEMM core v3 — BK=64 K-loop (half the barriers/staging setup per MFMA),
//     XOR-swizzled LDS tile layout (swizzle on the global source chunk, since
//     global_load_lds pins LDS dest to base+lane*16; fragment ds_read_b128s
//     now spread across all 32 banks), single-pass LDS-staged epilogue
//     (2 barriers, not 4), fast-erf gelu (~9 VALU vs ~30 for libm erff).
// ---------------------------------------------------------------------------

typedef _Float16 f16;
typedef _Float16 f16x8 __attribute__((ext_vector_type(8)));
typedef float floatx4 __attribute__((ext_vector_type(4)));

#define EP_BIAS_F16      0
#define EP_DECAY_F16     1
#define EP_BIAS_GELU_F16 2
#define EP_PARTIAL_F32   3

template <bool F32> struct out_sel { typedef f16 T; };
template <> struct out_sel<true>   { typedef float T; };

__device__ __forceinline__ void gload_lds16(const void* g, void* s) {
    __builtin_amdgcn_global_load_lds(
        (const __attribute__((address_space(1))) unsigned int*)g,
        (__attribute__((address_space(3))) unsigned int*)s, 16, 0, 0);
}

// erf via Abramowitz-Stegun 7.1.26, |abs err| <= 1.5e-7
__device__ __forceinline__ float erf_fast(float x) {
    const float ax = fabsf(x);
    const float t  = __builtin_amdgcn_rcpf(1.f + 0.3275911f * ax);
    const float p  = t * (0.254829592f + t * (-0.284496736f + t * (1.421413741f +
                     t * (-1.453152027f + t * 1.061405429f))));
    const float r  = 1.f - p * __expf(-ax * ax);
    return copysignf(r, x);
}

// C[m,n] = sum_k A[m,k] * B[n,k]  ("BT" form). 256 thr = 4 waves, 2x2 grid.
// blockIdx.z packs ((zo*inner + zi)*nsplit + ks); split ks covers K-range
// [ks*Kc,(ks+1)*Kc), partial written at cOff + ks*sCk (EP_PARTIAL_F32).
// K (and Kc) must be multiples of 64.
template <int BM, int BN, int WM, int WN, int EP>
__global__ __launch_bounds__(256, 4) void gemm_bt(
    const f16* __restrict__ A, const f16* __restrict__ B, void* __restrict__ Cv,
    int M, int N, int K, int lda, int ldb, int ldc,
    long long sAo, long long sAi, long long sBo, long long sBi,
    long long sCo, long long sCi, int inner,
    int nsplit, int Kc, long long sCk,
    const float* __restrict__ bias,
    const void* __restrict__ aux, long long sXo, long long sXi, int ldaux)
{
    constexpr bool OUT_F32 = (EP == EP_PARTIAL_F32);
    typedef typename out_sel<OUT_F32>::T OutT;
    constexpr int ESIZE       = OUT_F32 ? 4 : 2;
    constexpr int CSTRIDE     = BN + 4;                  // stage row stride, elems
    constexpr int TILE_BYTES  = (BM + BN) * 64 * 2;      // BK=64 f16 tiles
    constexpr int STAGE_BYTES = BM * CSTRIDE * ESIZE;    // full-tile C stage
    constexpr int SMEM_BYTES  = TILE_BYTES > STAGE_BYTES ? TILE_BYTES : STAGE_BYTES;

    __shared__ __align__(16) char smem[SMEM_BYTES];
    f16*  As = (f16*)smem;
    f16*  Bs = (f16*)(smem + BM * 128);
    OutT* Cs = (OutT*)smem;

    int z = blockIdx.z;
    const int ks = z % nsplit; z /= nsplit;
    const int zo = z / inner, zi = z % inner;
    A += zo * sAo + zi * sAi;
    B += zo * sBo + zi * sBi;
    const long long cOff = (long long)zo * sCo + (long long)zi * sCi + (long long)ks * sCk;
    const long long xOff = (long long)zo * sXo + (long long)zi * sXi;

    const int m0 = blockIdx.y * BM;
    const int n0 = blockIdx.x * BN;

    const int t    = threadIdx.x;
    const int lane = t & 63;
    const int w    = t >> 6;
    const int wm   = (w >> 1) * (WM * 16);
    const int wn   = (w & 1) * (WN * 16);
    const int fr   = lane & 15;          // A/B row within 16-tile
    const int quad = lane >> 4;          // 0..3, k-offset quad*8

    constexpr int ACH = BM / 32;         // 16B chunks per thread for A tile
    constexpr int BCH = BN / 32;

    floatx4 acc[WM][WN] = {};

    const int kbeg = ks * Kc, kend = kbeg + Kc;
    for (int kk = kbeg; kk < kend; kk += 64) {
        // async global->LDS, 16B/lane. LDS layout XOR-swizzled: LDS chunk
        // (r, sc) holds global chunk (r, sc ^ (r&7)); achieved by permuting
        // the global source per lane (dest is forced to base + lane*16).
#pragma unroll
        for (int i = 0; i < ACH; ++i) {
            const int ci = t + i * 256;
            const int r  = ci >> 3;
            const int c  = ((ci & 7) ^ (r & 7)) * 8;
            gload_lds16(A + (size_t)(m0 + r) * lda + kk + c, &As[ci * 8]);
        }
#pragma unroll
        for (int i = 0; i < BCH; ++i) {
            const int ci = t + i * 256;
            const int r  = ci >> 3;
            const int c  = ((ci & 7) ^ (r & 7)) * 8;
            gload_lds16(B + (size_t)(n0 + r) * ldb + kk + c, &Bs[ci * 8]);
        }
        __syncthreads();

#pragma unroll
        for (int kh = 0; kh < 2; ++kh) {
            const int cc = kh * 4 + quad;             // 16B chunk within row
            f16x8 af[WM], bf[WN];
#pragma unroll
            for (int tm = 0; tm < WM; ++tm) {
                const int r = wm + tm * 16 + fr;
                af[tm] = *(const f16x8*)&As[(r * 8 + (cc ^ (r & 7))) * 8];
            }
#pragma unroll
            for (int tn = 0; tn < WN; ++tn) {
                const int r = wn + tn * 16 + fr;
                bf[tn] = *(const f16x8*)&Bs[(r * 8 + (cc ^ (r & 7))) * 8];
            }
#pragma unroll
            for (int tm = 0; tm < WM; ++tm)
#pragma unroll
                for (int tn = 0; tn < WN; ++tn)
                    acc[tm][tn] = __builtin_amdgcn_mfma_f32_16x16x32_f16(af[tm], bf[tn], acc[tm][tn], 0, 0, 0);
        }
        __syncthreads();
    }

    // ---- epilogue: C/D layout col=lane&15, row=(lane>>4)*4+reg [m89] ----
    // Single pass: all waves stage their quadrant, one barrier, coalesced flush.
    const int er = quad * 4;
    const int ec = lane & 15;
#pragma unroll
    for (int tm = 0; tm < WM; ++tm) {
#pragma unroll
        for (int tn = 0; tn < WN; ++tn) {
#pragma unroll
            for (int r = 0; r < 4; ++r) {
                const int lrow = wm + tm * 16 + er + r;       // 0..BM-1
                const int col  = wn + tn * 16 + ec;           // 0..BN-1
                const int grow = m0 + lrow;
                const int gcol = n0 + col;
                const float v = acc[tm][tn][r];
                float val;
                if constexpr (EP == EP_BIAS_F16) {
                    val = v + bias[gcol];
                } else if constexpr (EP == EP_DECAY_F16) {
                    const float* dk = (const float*)aux + xOff;
                    val = v * dk[(size_t)grow * ldaux + gcol];
                } else if constexpr (EP == EP_BIAS_GELU_F16) {
                    const float u = v + bias[gcol];
                    val = 0.5f * u * (1.f + erf_fast(u * 0.70710678118f));
                } else {
                    val = v;
                }
                Cs[lrow * CSTRIDE + col] = (OutT)val;
            }
        }
    }
    __syncthreads();

    constexpr int PER_ROW = BN * ESIZE / 16;          // 16B chunks per row
    constexpr int NCHUNK  = (BM * PER_ROW) / 256;     // chunks per thread
#pragma unroll
    for (int i = 0; i < NCHUNK; ++i) {
        const int j  = t + i * 256;
        const int rr = j / PER_ROW;
        const int cc = j - rr * PER_ROW;
        const char* src = smem + (size_t)rr * (CSTRIDE * ESIZE) + (size_t)cc * 16;
        uint4 val;
        if constexpr (OUT_F32) {
            val = *(const uint4*)src;                 // stride 272B: 16B-aligned
        } else {
            const uint2 lo = *(const uint2*)src;      // stride 264B: 8B-aligned
            const uint2 hi = *(const uint2*)(src + 8);
            val = make_uint4(lo.x, lo.y, hi.x, hi.y);
        }
        char* dst = (char*)Cv +
            (size_t)(cOff + (long long)(m0 + rr) * ldc + n0) * ESIZE +
            (size_t)cc * 16;
        *(uint4*)dst = val;
    }
}

// out[4096,1024] = P0 + P1 + bias[col] + res   (all f32, float4 vectorized)
__global__ __launch_bounds__(256) void reduce2_bias_res(
    const float4* __restrict__ P, const float* __restrict__ bias,
    const float4* __restrict__ res, float4* __restrict__ out)
{
    const int i = blockIdx.x * 256 + threadIdx.x;   // 1,048,576 groups
    const int col4 = i & 255;
    const float4 a = P[i];
    const float4 b = P[i + 1048576];
    const float4 r = res[i];
    const float4 bi = ((const float4*)bias)[col4];
    float4 o;
    o.x = a.x + b.x + r.x + bi.x;
    o.y = a.y + b.y + r.y + bi.y;
    o.z = a.z + b.z + r.z + bi.z;
    o.w = a.w + b.w + r.w + bi.w;
    out[i] = o;
}

// gated_b[l, h*64+d] = (sum_ks P[h][ks][l][d]) * silu(xo_b[l, h*64+d])
__global__ __launch_bounds__(256) void reduce_gate(
    const float* __restrict__ P, const f16* __restrict__ xo, f16* __restrict__ gated)
{
    const int i = blockIdx.x * 256 + threadIdx.x;   // 262,144 groups of 4
    const int c = (i * 4) & 1023;
    const int l = (i * 4) >> 10;
    const int h = c >> 6, d = c & 63;
    const size_t base = (size_t)h * 262144 + (size_t)l * 64 + d;
    float4 s = {0.f, 0.f, 0.f, 0.f};
#pragma unroll
    for (int ks = 0; ks < 4; ++ks) {
        const float4 v = *(const float4*)(P + base + (size_t)ks * 65536);
        s.x += v.x; s.y += v.y; s.z += v.z; s.w += v.w;
    }
    alignas(8) f16 g[4];
    *(uint2*)g = *(const uint2*)(xo + (size_t)l * 4096 + c);
    alignas(8) f16 o[4];
    float sv[4] = {s.x, s.y, s.z, s.w};
#pragma unroll
    for (int j = 0; j < 4; ++j) {
        float gv = (float)g[j];
        gv = gv * __builtin_amdgcn_rcpf(1.f + __expf(-gv));
        o[j] = (f16)(sv[j] * gv);
    }
    *(uint2*)(gated + (size_t)l * 1024 + c) = *(uint2*)o;
}

// LayerNorm over D=1024, one block (256 thr) per row, fp16 output.
__global__ __launch_bounds__(256) void ln_to_f16(
    const float* __restrict__ x, const float* __restrict__ g,
    const float* __restrict__ b, f16* __restrict__ out)
{
    const int row = blockIdx.x;
    const int t = threadIdx.x;
    const float4 xv = ((const float4*)(x + (size_t)row * 1024))[t];
    float s  = xv.x + xv.y + xv.z + xv.w;
    float ss = xv.x * xv.x + xv.y * xv.y + xv.z * xv.z + xv.w * xv.w;
    for (int o = 32; o > 0; o >>= 1) {
        s  += __shfl_down(s, o, 64);
        ss += __shfl_down(ss, o, 64);
    }
    __shared__ float red[8];
    const int wv = t >> 6;
    if ((t & 63) == 0) { red[wv] = s; red[wv + 4] = ss; }
    __syncthreads();
    s  = red[0] + red[1] + red[2] + red[3];
    ss = red[4] + red[5] + red[6] + red[7];
    const float mean = s * (1.f / 1024.f);
    const float var  = ss * (1.f / 1024.f) - mean * mean;
    const float rstd = rsqrtf(var + 1e-5f);
    const float4 gv = ((const float4*)g)[t];
    const float4 bv = ((const float4*)b)[t];
    alignas(8) f16 h[4];
    h[0] = (f16)((xv.x - mean) * rstd * gv.x + bv.x);
    h[1] = (f16)((xv.y - mean) * rstd * gv.y + bv.y);
    h[2] = (f16)((xv.z - mean) * rstd * gv.z + bv.z);
    h[3] = (f16)((xv.w - mean) * rstd * gv.w + bv.w);
    ((uint2*)(out + (size_t)row * 1024))[t] = *(uint2*)h;
}

// f32 -> f16 cast, 4 elems/thread
__global__ __launch_bounds__(256) void cast_f32_f16(
    const float* __restrict__ in, f16* __restrict__ out, int n4)
{
    const int i = blockIdx.x * 256 + threadIdx.x;
    if (i < n4) {
        const float4 v = ((const float4*)in)[i];
        alignas(8) f16 h[4] = {(f16)v.x, (f16)v.y, (f16)v.z, (f16)v.w};
        ((uint2*)out)[i] = *(uint2*)h;
    }
}

// vT[z=(b*16+h)][d][m] = p[b*1024+m][2048 + h*64 + d]   (64x64 LDS tile)
__global__ __launch_bounds__(256) void transpose_v(
    const f16* __restrict__ p, f16* __restrict__ vT)
{
    const int z = blockIdx.y;
    const int b = z >> 4, h = z & 15;
    const int m0 = blockIdx.x * 64;
    __shared__ f16 tile[64][72];
    const int t = threadIdx.x;
    const f16* src = p + (size_t)(b * 1024 + m0) * 4096 + 2048 + h * 64;
#pragma unroll
    for (int pass = 0; pass < 4; ++pass) {
        const int r = (t >> 4) + pass * 16;   // m
        const int c = (t & 15) * 4;           // d
        *(uint2*)&tile[r][c] = *(const uint2*)(src + (size_t)r * 4096 + c);
    }
    __syncthreads();
    f16* dst = vT + (size_t)z * 65536 + m0;
#pragma unroll
    for (int pass = 0; pass < 4; ++pass) {
        const int d  = (t >> 4) + pass * 16;
        const int mc = (t & 15) * 4;
        alignas(8) f16 tmp[4] = {tile[mc][d], tile[mc + 1][d], tile[mc + 2][d], tile[mc + 3][d]};
        *(uint2*)(dst + (size_t)d * 1024 + mc) = *(uint2*)tmp;
    }
}

extern "C" void kernel_launch(void* const* d_in, const int* in_sizes, int n_in,
                              void* d_out, int out_size, void* d_ws, size_t ws_size,
                              hipStream_t stream) {
    const float* x      = (const float*)d_in[0];
    const float* decay  = (const float*)d_in[1];
    const float* ln1_g  = (const float*)d_in[2];
    const float* ln1_b  = (const float*)d_in[3];
    const float* proj_W = (const float*)d_in[4];
    const float* proj_b = (const float*)d_in[5];
    const float* reto_W = (const float*)d_in[6];
    const float* reto_b = (const float*)d_in[7];
    const float* ln2_g  = (const float*)d_in[8];
    const float* ln2_b  = (const float*)d_in[9];
    const float* ffn1_W = (const float*)d_in[10];
    const float* ffn1_b = (const float*)d_in[11];
    const float* ffn2_W = (const float*)d_in[12];
    const float* ffn2_b = (const float*)d_in[13];
    float* out = (float*)d_out;

    // Workspace (114 MB, liveness-aliased):
    //   Wp 8MB [cast..G1] -> gated [G3red..G4]
    //   Wr 2MB, W1 8MB, W2 8MB
    //   buf8 8MB: lnx[LN1..G1] -> vT[transp..G3] -> hln[LN2..G5]
    //   p 32MB [G1..G3red(xo)] -> ffh [G5..G6]
    //   S 32MB: scores per batch [G2..G3]; then G4/G6 splitK partials (2x16MB)
    //   y 16MB: G3 splitK partials per batch [G3..G3red]; then y [G4red..G6]
    char* w = (char*)d_ws;
    auto alloc = [&](size_t bytes) { char* r = w; w += (bytes + 255) & ~(size_t)255; return r; };
    f16*   Wp   = (f16*)alloc((size_t)4096 * 1024 * 2);
    f16*   Wr   = (f16*)alloc((size_t)1024 * 1024 * 2);
    f16*   W1   = (f16*)alloc((size_t)4096 * 1024 * 2);
    f16*   W2   = (f16*)alloc((size_t)1024 * 4096 * 2);
    f16*   buf8 = (f16*)alloc((size_t)4096 * 1024 * 2);
    f16*   p    = (f16*)alloc((size_t)4096 * 4096 * 2);
    f16*   S    = (f16*)alloc((size_t)16 * 1024 * 1024 * 2);
    float* y    = (float*)alloc((size_t)4096 * 1024 * 4);

    f16*   lnx   = buf8;
    f16*   vT    = buf8;
    f16*   hln   = buf8;
    f16*   gated = Wp;
    f16*   ffh   = p;
    float* Pk    = (float*)S;   // split-K partials for G4/G6 (2 x 16MB)
    float* Pg    = y;           // split-K partials for G3 (16MB, per batch)

    // weight casts
    cast_f32_f16<<<4096, 256, 0, stream>>>(proj_W, Wp, 1048576);
    cast_f32_f16<<<1024, 256, 0, stream>>>(reto_W, Wr, 262144);
    cast_f32_f16<<<4096, 256, 0, stream>>>(ffn1_W, W1, 1048576);
    cast_f32_f16<<<4096, 256, 0, stream>>>(ffn2_W, W2, 1048576);

    // LN1
    ln_to_f16<<<4096, 256, 0, stream>>>(x, ln1_g, ln1_b, lnx);

    // G1: p = lnx @ proj_W^T + proj_b     [4096,4096] K=1024
    gemm_bt<128, 128, 4, 4, EP_BIAS_F16><<<dim3(32, 32, 1), 256, 0, stream>>>(
        lnx, Wp, p, 4096, 4096, 1024, 1024, 1024, 4096,
        0, 0, 0, 0, 0, 0, 1, 1, 1024, 0, proj_b, nullptr, 0, 0, 0);

    // v transpose (overwrites lnx, dead after G1)
    transpose_v<<<dim3(16, 64), 256, 0, stream>>>(p, vT);

    // Attention, chunked per batch (S + Pg reused; stream order serializes)
    for (int b = 0; b < 4; ++b) {
        const f16* qb = p + (size_t)b * 4194304;
        const f16* kb = p + 1024 + (size_t)b * 4194304;
        // G2b: S[h] = q_b @ k_b^T * decay[h]   [1024,1024] K=64, z=h
        gemm_bt<128, 128, 4, 4, EP_DECAY_F16><<<dim3(8, 8, 16), 256, 0, stream>>>(
            qb, kb, S, 1024, 1024, 64, 4096, 4096, 1024,
            0, 64, 0, 64, 0, 1048576, 16, 1, 64, 0,
            nullptr, decay, 0, 1048576, 1024);
        // G3b: Pg[h][ks][l][d] = S[h] @ vT_bh^T over K-chunk ks  (split-K=4)
        gemm_bt<128, 64, 4, 2, EP_PARTIAL_F32><<<dim3(1, 8, 64), 256, 0, stream>>>(
            S, vT + (size_t)b * 1048576, Pg, 1024, 64, 1024, 1024, 1024, 64,
            0, 1048576, 0, 65536, 0, 262144, 16, 4, 256, 65536,
            nullptr, nullptr, 0, 0, 0);
        // gate: gated_b = (sum Pg) * silu(xo_b)
        reduce_gate<<<1024, 256, 0, stream>>>(
            Pg, p + 3072 + (size_t)b * 4194304, gated + (size_t)b * 1048576);
    }

    // G4: Pk = gated @ reto_W^T  (split-K=2, Kc=512) -> y = +reto_b + x
    gemm_bt<128, 64, 4, 2, EP_PARTIAL_F32><<<dim3(16, 32, 2), 256, 0, stream>>>(
        gated, Wr, Pk, 4096, 1024, 1024, 1024, 1024, 1024,
        0, 0, 0, 0, 0, 0, 1, 2, 512, 4194304, nullptr, nullptr, 0, 0, 0);
    reduce2_bias_res<<<4096, 256, 0, stream>>>(
        (const float4*)Pk, reto_b, (const float4*)x, (float4*)y);

    // LN2
    ln_to_f16<<<4096, 256, 0, stream>>>(y, ln2_g, ln2_b, hln);

    // G5: ffh = gelu(hln @ ffn1_W^T + ffn1_b)   [4096,4096] K=1024
    gemm_bt<128, 128, 4, 4, EP_BIAS_GELU_F16><<<dim3(32, 32, 1), 256, 0, stream>>>(
        hln, W1, ffh, 4096, 4096, 1024, 1024, 1024, 4096,
        0, 0, 0, 0, 0, 0, 1, 1, 1024, 0, ffn1_b, nullptr, 0, 0, 0);

    // G6: Pk = ffh @ ffn2_W^T (split-K=2, Kc=2048) -> out = +ffn2_b + y
    gemm_bt<128, 64, 4, 2, EP_PARTIAL_F32><<<dim3(16, 32, 2), 256, 0, stream>>>(
        ffh, W2, Pk, 4096, 1024, 4096, 4096, 4096, 1024,
        0, 0, 0, 0, 0, 0, 1, 2, 2048, 4194304, nullptr, nullptr, 0, 0, 0);
    reduce2_bias_res<<<4096, 256, 0, stream>>>(
        (const float4*)Pk, ffn2_b, (const float4*)y, (float4*)out);
}